// Round 1
// 531.635 us; speedup vs baseline: 1.0463x; 1.0463x over previous
//
#include <hip/hip_runtime.h>

typedef __bf16 bf16;
typedef bf16 bf16x2 __attribute__((ext_vector_type(2)));
typedef bf16 bf16x8 __attribute__((ext_vector_type(8)));
typedef float f32x4 __attribute__((ext_vector_type(4)));

#define B_ 4
#define T_ 4096
#define H_ 16
#define DK_ 64
#define DV_ 64
#define DMODEL_ 1024
#define M_ (B_ * T_)   // 16384
#define EPS_ 1e-6f

__device__ __forceinline__ void async_ld16(const void* g, void* l) {
    __builtin_amdgcn_global_load_lds(
        (const __attribute__((address_space(1))) unsigned int*)g,
        (__attribute__((address_space(3))) unsigned int*)l,
        16, 0, 0);
}

// T1 XCD-aware bijective block swizzle (nwg must be divisible by 8; here 1024).
// Dispatcher round-robins XCDs by linear block id; remap so each XCD owns
// a contiguous chunk of work ids. With n-fastest decomposition, each XCD
// owns nwg/(8*NT) consecutive A row-panels: A fetched once per panel, all 8
// n-tiles served from that XCD's L2.
__device__ __forceinline__ void swizzle_tiles(int& m0, int& n0) {
    const int nwg  = gridDim.x * gridDim.y;
    const int flat = blockIdx.y * gridDim.x + blockIdx.x;   // HW dispatch order
    const int swz  = (flat & 7) * (nwg >> 3) + (flat >> 3); // chunk per XCD
    n0 = (swz % gridDim.x) * 128;
    m0 = (swz / gridDim.x) * 128;
}

// ------------------------------------------- transpose + fp32->bf16 convert
struct TPtrs { const float* s[4]; bf16* d[4]; };

__global__ void transpose4(TPtrs p) {
    __shared__ bf16 t[32][33];
    const float* src = p.s[blockIdx.z];
    bf16*        dst = p.d[blockIdx.z];
    const int tx = threadIdx.x, ty = threadIdx.y;
    const int x  = blockIdx.x * 32 + tx;
    const int y0 = blockIdx.y * 32 + ty;
#pragma unroll
    for (int i = 0; i < 32; i += 8)
        t[ty + i][tx] = (bf16)src[(size_t)(y0 + i) * 1024 + x];
    __syncthreads();
    const int xo = blockIdx.y * 32 + tx;   // k index
    const int yo = blockIdx.x * 32 + ty;   // n index
#pragma unroll
    for (int i = 0; i < 32; i += 8)
        dst[(size_t)(yo + i) * 1024 + xo] = t[tx][ty + i];
}

// ----------------------------------------------- fp32 -> bf16 convert pass
// one thread per 8 elements: 2x float4 load, 1x 16B store. Memory-bound.
__global__ __launch_bounds__(256) void cvt_kernel(
    const float* __restrict__ src, bf16* __restrict__ dst)
{
    const size_t i = (size_t)blockIdx.x * 256 + threadIdx.x;  // per 8 elems
    const float4* s = (const float4*)src + 2 * i;
    float4 a = s[0];
    float4 b = s[1];
    bf16x8 h;
    h[0] = (bf16)a.x; h[1] = (bf16)a.y; h[2] = (bf16)a.z; h[3] = (bf16)a.w;
    h[4] = (bf16)b.x; h[5] = (bf16)b.y; h[6] = (bf16)b.z; h[7] = (bf16)b.w;
    *(bf16x8*)(dst + 8 * i) = h;
}

// ---------------------------------------------------- GEMM, all-bf16 (m97)
// C[M,N] = act(A[M,K] @ Bt[N,K]^T + bias[N]); act=1 -> phi(x)=elu(x)+1
__global__ __launch_bounds__(256) void gemm_bt_kernel(
    const bf16* __restrict__ A, const bf16* __restrict__ Bt,
    const float* __restrict__ bias, bf16* __restrict__ C,
    int M, int N, int K, int act)
{
    __shared__ bf16 As[128 * 32];
    __shared__ bf16 Bs[128 * 32];

    const int tid  = threadIdx.x;
    const int wave = tid >> 6;
    const int lane = tid & 63;
    int m0, n0;
    swizzle_tiles(m0, n0);
    const int wm = (wave >> 1) * 64;
    const int wn = (wave & 1) * 64;
    const int fr = lane & 15;
    const int fk = (lane >> 4) * 8;

    f32x4 acc[4][4] = {};

    const int c0 = wave * 64 + lane;
    const int c1 = c0 + 256;
    const int rA0 = c0 >> 2, kA0 = (c0 & 3) * 8;
    const int rA1 = c1 >> 2, kA1 = (c1 & 3) * 8;
    const bf16* gA0 = A  + (size_t)(m0 + rA0) * K + kA0;
    const bf16* gA1 = A  + (size_t)(m0 + rA1) * K + kA1;
    const bf16* gB0 = Bt + (size_t)(n0 + rA0) * K + kA0;
    const bf16* gB1 = Bt + (size_t)(n0 + rA1) * K + kA1;
    char* lA0 = (char*)As + (size_t)(wave * 64) * 16;
    char* lA1 = lA0 + 4096;
    char* lB0 = (char*)Bs + (size_t)(wave * 64) * 16;
    char* lB1 = lB0 + 4096;

    for (int kt = 0; kt < K; kt += 32) {
        async_ld16(gA0 + kt, lA0);
        async_ld16(gA1 + kt, lA1);
        async_ld16(gB0 + kt, lB0);
        async_ld16(gB1 + kt, lB1);
        __syncthreads();
        bf16x8 af[4], bfr[4];
#pragma unroll
        for (int i = 0; i < 4; ++i)
            af[i] = *(const bf16x8*)&As[(wm + i * 16 + fr) * 32 + fk];
#pragma unroll
        for (int j = 0; j < 4; ++j)
            bfr[j] = *(const bf16x8*)&Bs[(wn + j * 16 + fr) * 32 + fk];
#pragma unroll
        for (int i = 0; i < 4; ++i)
#pragma unroll
            for (int j = 0; j < 4; ++j)
                acc[i][j] = __builtin_amdgcn_mfma_f32_16x16x32_bf16(
                    af[i], bfr[j], acc[i][j], 0, 0, 0);
        __syncthreads();
    }

    // epilogue: D[row=(lane>>4)*4+r][col=lane&15] per 16x16 tile
#pragma unroll
    for (int j = 0; j < 4; ++j) {
        const int col = n0 + wn + j * 16 + fr;
        const float bb = bias[col];
#pragma unroll
        for (int i = 0; i < 4; ++i) {
            const int row = m0 + wm + i * 16 + (lane >> 4) * 4;
#pragma unroll
            for (int r = 0; r < 4; ++r) {
                float x = acc[i][j][r] + bb;
                if (act) x = (x > 0.0f) ? (x + 1.0f) : __expf(x);
                C[(size_t)(row + r) * N + col] = (bf16)x;
            }
        }
    }
}

// ------------------------------------- GEMM, bf16 in, OUTPUT = fp32 (O-proj)
__global__ __launch_bounds__(256) void gemm_bt_f32out_kernel(
    const bf16* __restrict__ A, const bf16* __restrict__ Bt,
    const float* __restrict__ bias, float* __restrict__ C,
    int M, int N, int K)
{
    __shared__ bf16 As[128 * 32];
    __shared__ bf16 Bs[128 * 32];

    const int tid  = threadIdx.x;
    const int wave = tid >> 6;
    const int lane = tid & 63;
    int m0, n0;
    swizzle_tiles(m0, n0);
    const int wm = (wave >> 1) * 64;
    const int wn = (wave & 1) * 64;
    const int fr = lane & 15;
    const int fk = (lane >> 4) * 8;

    f32x4 acc[4][4] = {};

    const int c0 = wave * 64 + lane;
    const int c1 = c0 + 256;
    const int rA0 = c0 >> 2, kA0 = (c0 & 3) * 8;
    const int rA1 = c1 >> 2, kA1 = (c1 & 3) * 8;
    const bf16* gA0 = A  + (size_t)(m0 + rA0) * K + kA0;
    const bf16* gA1 = A  + (size_t)(m0 + rA1) * K + kA1;
    const bf16* gB0 = Bt + (size_t)(n0 + rA0) * K + kA0;
    const bf16* gB1 = Bt + (size_t)(n0 + rA1) * K + kA1;
    char* lA0 = (char*)As + (size_t)(wave * 64) * 16;
    char* lA1 = lA0 + 4096;
    char* lB0 = (char*)Bs + (size_t)(wave * 64) * 16;
    char* lB1 = lB0 + 4096;

    for (int kt = 0; kt < K; kt += 32) {
        async_ld16(gA0 + kt, lA0);
        async_ld16(gA1 + kt, lA1);
        async_ld16(gB0 + kt, lB0);
        async_ld16(gB1 + kt, lB1);
        __syncthreads();
        bf16x8 af[4], bfr[4];
#pragma unroll
        for (int i = 0; i < 4; ++i)
            af[i] = *(const bf16x8*)&As[(wm + i * 16 + fr) * 32 + fk];
#pragma unroll
        for (int j = 0; j < 4; ++j)
            bfr[j] = *(const bf16x8*)&Bs[(wn + j * 16 + fr) * 32 + fk];
#pragma unroll
        for (int i = 0; i < 4; ++i)
#pragma unroll
            for (int j = 0; j < 4; ++j)
                acc[i][j] = __builtin_amdgcn_mfma_f32_16x16x32_bf16(
                    af[i], bfr[j], acc[i][j], 0, 0, 0);
        __syncthreads();
    }

#pragma unroll
    for (int j = 0; j < 4; ++j) {
        const int col = n0 + wn + j * 16 + fr;
        const float bb = bias[col];
#pragma unroll
        for (int i = 0; i < 4; ++i) {
            const int row = m0 + wm + i * 16 + (lane >> 4) * 4;
#pragma unroll
            for (int r = 0; r < 4; ++r)
                C[(size_t)(row + r) * N + col] = acc[i][j][r] + bb;
        }
    }
}

// -------------------------------------------------- kv partial accumulation
__global__ __launch_bounds__(256) void kv_partial_kernel(
    const bf16* __restrict__ Kb, const bf16* __restrict__ V,
    float* __restrict__ kv_part, float* __restrict__ ksum_part)
{
    const int bh = blockIdx.y;
    const int b  = bh >> 4;
    const int h  = bh & 15;
    const int tc = blockIdx.x;
    const int TC = T_ / 8;           // 512
    const int t0 = tc * TC;

    __shared__ float kb[8][64];
    __shared__ float vb[8][64];

    const int tid = threadIdx.x;
    const int dvq = tid >> 4;
    const int dkq = tid & 15;
    const int lr  = tid >> 5;
    const int lc  = (tid & 31) << 1;

    float acc[4][4] = {};
    float ksacc = 0.0f;

    for (int tt0 = 0; tt0 < TC; tt0 += 8) {
        const size_t base = ((size_t)(b * T_) + t0 + tt0 + lr) * 1024 + h * 64 + lc;
        bf16x2 k2 = *(const bf16x2*)&Kb[base];
        bf16x2 v2 = *(const bf16x2*)&V[base];
        kb[lr][lc] = (float)k2[0]; kb[lr][lc + 1] = (float)k2[1];
        vb[lr][lc] = (float)v2[0]; vb[lr][lc + 1] = (float)v2[1];
        __syncthreads();
#pragma unroll
        for (int tt = 0; tt < 8; ++tt) {
            float4 vv = *(const float4*)&vb[tt][dvq * 4];
            float4 kk = *(const float4*)&kb[tt][dkq * 4];
            float va[4] = {vv.x, vv.y, vv.z, vv.w};
            float ka[4] = {kk.x, kk.y, kk.z, kk.w};
#pragma unroll
            for (int i = 0; i < 4; ++i)
#pragma unroll
                for (int j = 0; j < 4; ++j)
                    acc[i][j] += va[i] * ka[j];
        }
        if (tid < 64) {
#pragma unroll
            for (int tt = 0; tt < 8; ++tt) ksacc += kb[tt][tid];
        }
        __syncthreads();
    }

    float* kvp = kv_part + ((size_t)tc * 64 + bh) * 4096;
#pragma unroll
    for (int i = 0; i < 4; ++i) {
        float4 w = make_float4(acc[i][0], acc[i][1], acc[i][2], acc[i][3]);
        *(float4*)&kvp[(dvq * 4 + i) * 64 + dkq * 4] = w;
    }
    if (tid < 64)
        ksum_part[((size_t)tc * 64 + bh) * 64 + tid] = ksacc;
}

// ------------------------------------------------------------- kv reduction
__global__ __launch_bounds__(256) void kv_reduce_kernel(
    const float* __restrict__ kv_part, const float* __restrict__ ksum_part,
    bf16* __restrict__ kvb, float* __restrict__ ksum)
{
    const int bh = blockIdx.x;
    const int tid = threadIdx.x;
    for (int e = tid; e < 4096; e += 256) {
        float s = 0.0f;
#pragma unroll
        for (int tc = 0; tc < 8; ++tc)
            s += kv_part[((size_t)tc * 64 + bh) * 4096 + e];
        kvb[(size_t)bh * 4096 + e] = (bf16)s;
    }
    if (tid < 64) {
        float s = 0.0f;
#pragma unroll
        for (int tc = 0; tc < 8; ++tc)
            s += ksum_part[((size_t)tc * 64 + bh) * 64 + tid];
        ksum[bh * 64 + tid] = s;
    }
}

// ------------------------------------------------------------------ attn
__global__ __launch_bounds__(256) void attn_kernel(
    const bf16* __restrict__ Q, const bf16* __restrict__ kvb,
    const float* __restrict__ ksum, bf16* __restrict__ attn)
{
    const int bh = blockIdx.y;
    const int b  = bh >> 4;
    const int h  = bh & 15;
    const int t0 = blockIdx.x * 128;

    __shared__ bf16 As[128 * 64];
    __shared__ bf16 Bs[64 * 64];
    __shared__ float ksum_s[64];
    __shared__ float norm_s[128];

    const int tid  = threadIdx.x;
    const int wave = tid >> 6;
    const int lane = tid & 63;

    const bf16* Qbase = Q + ((size_t)(b * T_) + t0) * 1024 + h * 64;

#pragma unroll
    for (int r2 = 0; r2 < 4; ++r2) {
        const int c   = r2 * 256 + wave * 64 + lane;
        const int row = c >> 3;
        const int ko  = (c & 7) * 8;
        char* l = (char*)As + (size_t)(r2 * 256 + wave * 64) * 16;
        async_ld16(Qbase + (size_t)row * 1024 + ko, l);
    }
    {
        const float4* src = (const float4*)(kvb + (size_t)bh * 4096);
        float4* dst = (float4*)Bs;
        for (int e = tid; e < 512; e += 256) dst[e] = src[e];
    }
    if (tid < 64) ksum_s[tid] = ksum[bh * 64 + tid];
    __syncthreads();

    if (tid < 128) {
        const bf16x8* qp = (const bf16x8*)(Qbase + (size_t)tid * 1024);
        float s = 0.0f;
#pragma unroll
        for (int u = 0; u < 8; ++u) {
            bf16x8 v = qp[u];
#pragma unroll
            for (int e = 0; e < 8; ++e) s += (float)v[e] * ksum_s[u * 8 + e];
        }
        norm_s[tid] = 1.0f / (s + EPS_);
    }
    __syncthreads();

    const int fr  = lane & 15;
    const int fkq = lane >> 4;
    f32x4 acc[2][4] = {};
#pragma unroll
    for (int ks = 0; ks < 2; ++ks) {
        bf16x8 af[2], bfr[4];
#pragma unroll
        for (int i = 0; i < 2; ++i)
            af[i] = *(const bf16x8*)&As[(wave * 32 + i * 16 + fr) * 64 + ks * 32 + fkq * 8];
#pragma unroll
        for (int j = 0; j < 4; ++j)
            bfr[j] = *(const bf16x8*)&Bs[(j * 16 + fr) * 64 + ks * 32 + fkq * 8];
#pragma unroll
        for (int i = 0; i < 2; ++i)
#pragma unroll
            for (int j = 0; j < 4; ++j)
                acc[i][j] = __builtin_amdgcn_mfma_f32_16x16x32_bf16(
                    af[i], bfr[j], acc[i][j], 0, 0, 0);
    }

    bf16* out = attn + ((size_t)(b * T_) + t0) * 1024 + h * 64;
#pragma unroll
    for (int i = 0; i < 2; ++i)
#pragma unroll
        for (int j = 0; j < 4; ++j)
#pragma unroll
            for (int r = 0; r < 4; ++r) {
                const int row = wave * 32 + i * 16 + fkq * 4 + r;
                const int col = j * 16 + fr;
                out[(size_t)row * 1024 + col] = (bf16)(acc[i][j][r] * norm_s[row]);
            }
}

// ---------------------------------------------------------------- launcher
// inputs fp32, OUTPUT fp32 (64 MiB). ws (<=48.7 MiB):
//  [0,8)   WT bf16 (WqT/WkT/WvT/WoT)
//  [8,40)  CVT slot (bf16 activation; later reused as ATTN)
//  [40,48) kv_part fp32 | [48,+128K) ksum_part | +512K kvb | +16K ksum
// d_out doubles as scratch: KB in [0,32), VB in [32,64); Qb reuses [0,32)
// after kv; final O-GEMM overwrites all 64 MiB with fp32 output.
extern "C" void kernel_launch(void* const* d_in, const int* in_sizes, int n_in,
                              void* d_out, int out_size, void* d_ws, size_t ws_size,
                              hipStream_t stream) {
    const float* query = (const float*)d_in[0];
    const float* key_  = (const float*)d_in[1];
    const float* value = (const float*)d_in[2];
    const float* Wq = (const float*)d_in[3];
    const float* bq = (const float*)d_in[4];
    const float* Wk = (const float*)d_in[5];
    const float* bk = (const float*)d_in[6];
    const float* Wv = (const float*)d_in[7];
    const float* bv = (const float*)d_in[8];
    const float* Wo = (const float*)d_in[9];
    const float* bo = (const float*)d_in[10];

    char* ws = (char*)d_ws;
    char* out8 = (char*)d_out;
    const size_t MB = 1024 * 1024;
    bf16* WqT = (bf16*)(ws + 0 * MB);
    bf16* WkT = (bf16*)(ws + 2 * MB);
    bf16* WvT = (bf16*)(ws + 4 * MB);
    bf16* WoT = (bf16*)(ws + 6 * MB);
    bf16* CVT = (bf16*)(ws + 8 * MB);                    // 32 MiB, reused 3x
    float* kv_part   = (float*)(ws + 40 * MB);           // 8 MiB
    float* ksum_part = (float*)(ws + 48 * MB);           // 128 KiB
    bf16*  kvb  = (bf16*)(ws + 48 * MB + 128 * 1024);    // 512 KiB
    float* ksum = (float*)(ws + 48 * MB + 640 * 1024);   // 16 KiB

    bf16* KB   = (bf16*)out8;                            // d_out [0,32)
    bf16* VB   = (bf16*)(out8 + 32 * MB);                // d_out [32,64)
    bf16* Qb   = (bf16*)out8;                            // reused after kv
    bf16* ATTN = CVT;                                    // reuses CVT slot

    TPtrs tp;
    tp.s[0] = Wq;  tp.s[1] = Wk;  tp.s[2] = Wv;  tp.s[3] = Wo;
    tp.d[0] = WqT; tp.d[1] = WkT; tp.d[2] = WvT; tp.d[3] = WoT;
    transpose4<<<dim3(32, 32, 4), dim3(32, 8, 1), 0, stream>>>(tp);

    const int CVT_BLOCKS = M_ * 1024 / 8 / 256;          // 8192

    cvt_kernel<<<CVT_BLOCKS, 256, 0, stream>>>(key_, CVT);
    gemm_bt_kernel<<<dim3(8, 128), 256, 0, stream>>>(CVT, WkT, bk, KB, M_, 1024, 1024, 1);

    cvt_kernel<<<CVT_BLOCKS, 256, 0, stream>>>(value, CVT);
    gemm_bt_kernel<<<dim3(8, 128), 256, 0, stream>>>(CVT, WvT, bv, VB, M_, 1024, 1024, 0);

    kv_partial_kernel<<<dim3(8, 64), 256, 0, stream>>>(KB, VB, kv_part, ksum_part);
    kv_reduce_kernel<<<dim3(64), 256, 0, stream>>>(kv_part, ksum_part, kvb, ksum);

    cvt_kernel<<<CVT_BLOCKS, 256, 0, stream>>>(query, CVT);
    gemm_bt_kernel<<<dim3(8, 128), 256, 0, stream>>>(CVT, WqT, bq, Qb, M_, 1024, 1024, 1);

    attn_kernel<<<dim3(32, 64), 256, 0, stream>>>(Qb, kvb, ksum, ATTN);

    gemm_bt_f32out_kernel<<<dim3(8, 128), 256, 0, stream>>>(ATTN, WoT, bo, (float*)d_out, M_, 1024, 1024);
}

// Round 2
// 443.888 us; speedup vs baseline: 1.2532x; 1.1977x over previous
//
#include <hip/hip_runtime.h>

typedef __bf16 bf16;
typedef bf16 bf16x2 __attribute__((ext_vector_type(2)));
typedef bf16 bf16x8 __attribute__((ext_vector_type(8)));
typedef float f32x4 __attribute__((ext_vector_type(4)));

#define B_ 4
#define T_ 4096
#define H_ 16
#define DK_ 64
#define DV_ 64
#define DMODEL_ 1024
#define M_ (B_ * T_)   // 16384
#define EPS_ 1e-6f

#define BARX()  asm volatile("s_barrier" ::: "memory")
#define LGKM0() asm volatile("s_waitcnt lgkmcnt(0)" ::: "memory")

__device__ __forceinline__ void async_ld16(const void* g, void* l) {
    __builtin_amdgcn_global_load_lds(
        (const __attribute__((address_space(1))) unsigned int*)g,
        (__attribute__((address_space(3))) unsigned int*)l,
        16, 0, 0);
}

// ------------------------------------------- transpose + fp32->bf16 convert
struct TPtrs { const float* s[4]; bf16* d[4]; };

__global__ void transpose4(TPtrs p) {
    __shared__ bf16 t[32][33];
    const float* src = p.s[blockIdx.z];
    bf16*        dst = p.d[blockIdx.z];
    const int tx = threadIdx.x, ty = threadIdx.y;
    const int x  = blockIdx.x * 32 + tx;
    const int y0 = blockIdx.y * 32 + ty;
#pragma unroll
    for (int i = 0; i < 32; i += 8)
        t[ty + i][tx] = (bf16)src[(size_t)(y0 + i) * 1024 + x];
    __syncthreads();
    const int xo = blockIdx.y * 32 + tx;   // k index
    const int yo = blockIdx.x * 32 + ty;   // n index
#pragma unroll
    for (int i = 0; i < 32; i += 8)
        dst[(size_t)(yo + i) * 1024 + xo] = t[tx][ty + i];
}

// ----------------------------------------------- fp32 -> bf16 convert pass
__global__ __launch_bounds__(256) void cvt_kernel(
    const float* __restrict__ src, bf16* __restrict__ dst)
{
    const size_t i = (size_t)blockIdx.x * 256 + threadIdx.x;  // per 8 elems
    const float4* s = (const float4*)src + 2 * i;
    float4 a = s[0];
    float4 b = s[1];
    bf16x8 h;
    h[0] = (bf16)a.x; h[1] = (bf16)a.y; h[2] = (bf16)a.z; h[3] = (bf16)a.w;
    h[4] = (bf16)b.x; h[5] = (bf16)b.y; h[6] = (bf16)b.z; h[7] = (bf16)b.w;
    *(bf16x8*)(dst + 8 * i) = h;
}

// ===================== 256x256 8-phase GEMM (T1+T2+T3+T4+T5) =============
// C[M,N] = f(A[M,K] @ Bt[N,K]^T + bias[N])
// 8 waves (2M x 4N), per-wave 128x64 out, BK=64, dbuf LDS 128 KiB.
// LDS swizzle: within a 128B row, 16B slot s_phys = s_logical ^ (row&7).
// Staging writes linear (global_load_lds) with pre-swizzled global source.

// stage one half-tile (128 rows x 64 cols bf16): 2 loads/thread.
__device__ __forceinline__ void stage_half(
    const bf16* __restrict__ G, int base_rc, int K,
    char* lds_op_buf, int t, int h, int w, int lane)
{
    const int r8   = lane >> 3;                       // 0..7
    const int row  = h * 128 + w * 8 + r8;
    const int cole = (((lane & 7) ^ r8) << 3);        // pre-swizzled col
    const bf16* g = G + (size_t)(base_rc + row) * K + t * 64 + cole;
    char* l = lds_op_buf + h * 16384 + w * 1024;      // wave-uniform base
    async_ld16(g, l);
    async_ld16(g + (size_t)64 * K, l + 8192);         // +64 rows
}

template<int G>
__device__ __forceinline__ void read_a4(bf16x8 (&aF)[4][2], const char* ab,
                                        int arow, int fq, int l7) {
#pragma unroll
    for (int i = 0; i < 4; ++i)
#pragma unroll
        for (int ks = 0; ks < 2; ++ks)
            aF[i][ks] = *(const bf16x8*)(ab
                + (arow + (G * 4 + i) * 16) * 128
                + ((((ks << 2) + fq) ^ l7) << 4));
}

template<int JP>
__device__ __forceinline__ void read_b2(bf16x8 (&bF)[4][2], const char* bb,
                                        int brow, int fq, int l7) {
#pragma unroll
    for (int j = 0; j < 2; ++j)
#pragma unroll
        for (int ks = 0; ks < 2; ++ks)
            bF[JP * 2 + j][ks] = *(const bf16x8*)(bb
                + (brow + (JP * 2 + j) * 16) * 128
                + ((((ks << 2) + fq) ^ l7) << 4));
}

template<int G, int JP>
__device__ __forceinline__ void mfma_q(f32x4 (&acc)[8][4],
                                       const bf16x8 (&aF)[4][2],
                                       const bf16x8 (&bF)[4][2]) {
#pragma unroll
    for (int i = 0; i < 4; ++i)
#pragma unroll
        for (int j = 0; j < 2; ++j)
#pragma unroll
            for (int ks = 0; ks < 2; ++ks)
                acc[G * 4 + i][JP * 2 + j] =
                    __builtin_amdgcn_mfma_f32_16x16x32_bf16(
                        aF[i][ks], bF[JP * 2 + j][ks],
                        acc[G * 4 + i][JP * 2 + j], 0, 0, 0);
}

template<int ACT, int F32OUT>
__global__ __launch_bounds__(512, 2) void gemm256_kernel(
    const bf16* __restrict__ A, const bf16* __restrict__ Bt,
    const float* __restrict__ bias, void* __restrict__ Cout,
    int M, int N, int K)
{
    __shared__ f32x4 smem4[8192];          // 128 KiB
    char* smem = (char*)smem4;
    char* Ab0 = smem;                      // A buf0 (even tiles)
    char* Ab1 = smem + 32768;              // A buf1 (odd tiles)
    char* Bb0 = smem + 65536;
    char* Bb1 = smem + 98304;

    const int tid  = threadIdx.x;
    const int w    = tid >> 6, lane = tid & 63;
    const int wrow = w >> 2,  wcol = w & 3;
    const int fr = lane & 15, fq = lane >> 4, l7 = lane & 7;
    const int arow = wrow * 128 + fr;
    const int brow = wcol * 64 + fr;

    // T1 bijective XCD swizzle (nwg=256, divisible by 8)
    const int nwg  = gridDim.x * gridDim.y;
    const int flat = blockIdx.y * gridDim.x + blockIdx.x;
    const int swz  = (flat & 7) * (nwg >> 3) + (flat >> 3);
    const int n0   = (swz % gridDim.x) * 256;
    const int m0   = (swz / gridDim.x) * 256;

    const int KT = K >> 6;                 // 16 K-tiles

    f32x4  acc[8][4] = {};
    bf16x8 aF[4][2], bF[4][2];

    // prologue: tile0 {B0,A0,B1,A1}, tile1 {B0,A0}; keep 2 halves in flight
    stage_half(Bt, n0, K, Bb0, 0, 0, w, lane);
    stage_half(A,  m0, K, Ab0, 0, 0, w, lane);
    stage_half(Bt, n0, K, Bb0, 0, 1, w, lane);
    stage_half(A,  m0, K, Ab0, 0, 1, w, lane);
    stage_half(Bt, n0, K, Bb1, 1, 0, w, lane);
    stage_half(A,  m0, K, Ab1, 1, 0, w, lane);
    asm volatile("s_waitcnt vmcnt(4)" ::: "memory");   // tile0 landed
    BARX();

    for (int it = 0; it < (KT >> 1); ++it) {
        const int  t0   = it * 2, t1 = t0 + 1;
        const bool more = (it < (KT >> 1) - 1);

        // ---- P1: tile t0 (buf0) Q(0,0); stage B1(t1)
        read_a4<0>(aF, Ab0, arow, fq, l7);
        read_b2<0>(bF, Bb0, brow, fq, l7);
        stage_half(Bt, n0, K, Bb1, t1, 1, w, lane);
        asm volatile("s_waitcnt lgkmcnt(8)" ::: "memory");
        BARX(); LGKM0();
        __builtin_amdgcn_s_setprio(1);
        mfma_q<0, 0>(acc, aF, bF);
        __builtin_amdgcn_s_setprio(0);
        BARX();

        // ---- P2: Q(0,1); stage A1(t1)
        read_b2<1>(bF, Bb0, brow, fq, l7);
        stage_half(A, m0, K, Ab1, t1, 1, w, lane);
        BARX(); LGKM0();
        __builtin_amdgcn_s_setprio(1);
        mfma_q<0, 1>(acc, aF, bF);
        __builtin_amdgcn_s_setprio(0);
        BARX();

        // ---- P3: Q(1,0); stage B0(t0+2)
        read_a4<1>(aF, Ab0, arow, fq, l7);
        if (more) stage_half(Bt, n0, K, Bb0, t0 + 2, 0, w, lane);
        BARX(); LGKM0();
        __builtin_amdgcn_s_setprio(1);
        mfma_q<1, 0>(acc, aF, bF);
        __builtin_amdgcn_s_setprio(0);
        BARX();

        // ---- P4: Q(1,1); stage A0(t0+2); vm gate (tile t1 must be landed)
        if (more) {
            stage_half(A, m0, K, Ab0, t0 + 2, 0, w, lane);
            asm volatile("s_waitcnt vmcnt(4)" ::: "memory");
        } else {
            asm volatile("s_waitcnt vmcnt(0)" ::: "memory");  // final drain
        }
        BARX();
        __builtin_amdgcn_s_setprio(1);
        mfma_q<1, 1>(acc, aF, bF);
        __builtin_amdgcn_s_setprio(0);
        BARX();

        // ---- P5: tile t1 (buf1) Q(0,0); stage B1(t0+2)
        read_a4<0>(aF, Ab1, arow, fq, l7);
        read_b2<0>(bF, Bb1, brow, fq, l7);
        if (more) stage_half(Bt, n0, K, Bb0, t0 + 2, 1, w, lane);
        asm volatile("s_waitcnt lgkmcnt(8)" ::: "memory");
        BARX(); LGKM0();
        __builtin_amdgcn_s_setprio(1);
        mfma_q<0, 0>(acc, aF, bF);
        __builtin_amdgcn_s_setprio(0);
        BARX();

        // ---- P6: Q(0,1); stage A1(t0+2)
        read_b2<1>(bF, Bb1, brow, fq, l7);
        if (more) stage_half(A, m0, K, Ab0, t0 + 2, 1, w, lane);
        BARX(); LGKM0();
        __builtin_amdgcn_s_setprio(1);
        mfma_q<0, 1>(acc, aF, bF);
        __builtin_amdgcn_s_setprio(0);
        BARX();

        // ---- P7: Q(1,0); stage B0(t1+2)
        read_a4<1>(aF, Ab1, arow, fq, l7);
        if (more) stage_half(Bt, n0, K, Bb1, t1 + 2, 0, w, lane);
        BARX(); LGKM0();
        __builtin_amdgcn_s_setprio(1);
        mfma_q<1, 0>(acc, aF, bF);
        __builtin_amdgcn_s_setprio(0);
        BARX();

        // ---- P8: Q(1,1); stage A0(t1+2); vm gate (tile t0+2 must be landed)
        if (more) {
            stage_half(A, m0, K, Ab1, t1 + 2, 0, w, lane);
            asm volatile("s_waitcnt vmcnt(4)" ::: "memory");
        }
        BARX();
        __builtin_amdgcn_s_setprio(1);
        mfma_q<1, 1>(acc, aF, bF);
        __builtin_amdgcn_s_setprio(0);
        BARX();
    }

    // ---- epilogue: D[row=(lane>>4)*4+r][col=lane&15] per 16x16 tile
    const size_t Ns = (size_t)N;
#pragma unroll
    for (int g = 0; g < 8; ++g) {
#pragma unroll
        for (int j = 0; j < 4; ++j) {
            const int col = n0 + wcol * 64 + j * 16 + fr;
            const float bb = bias[col];
            const int row0 = m0 + wrow * 128 + g * 16 + fq * 4;
#pragma unroll
            for (int r = 0; r < 4; ++r) {
                float x = acc[g][j][r] + bb;
                if (ACT) x = (x > 0.0f) ? (x + 1.0f) : __expf(x);
                if (F32OUT)
                    ((float*)Cout)[(size_t)(row0 + r) * Ns + col] = x;
                else
                    ((bf16*)Cout)[(size_t)(row0 + r) * Ns + col] = (bf16)x;
            }
        }
    }
}

// -------------------------------------------------- kv partial accumulation
__global__ __launch_bounds__(256) void kv_partial_kernel(
    const bf16* __restrict__ Kb, const bf16* __restrict__ V,
    float* __restrict__ kv_part, float* __restrict__ ksum_part)
{
    const int bh = blockIdx.y;
    const int b  = bh >> 4;
    const int h  = bh & 15;
    const int tc = blockIdx.x;
    const int TC = T_ / 8;           // 512
    const int t0 = tc * TC;

    __shared__ float kb[8][64];
    __shared__ float vb[8][64];

    const int tid = threadIdx.x;
    const int dvq = tid >> 4;
    const int dkq = tid & 15;
    const int lr  = tid >> 5;
    const int lc  = (tid & 31) << 1;

    float acc[4][4] = {};
    float ksacc = 0.0f;

    for (int tt0 = 0; tt0 < TC; tt0 += 8) {
        const size_t base = ((size_t)(b * T_) + t0 + tt0 + lr) * 1024 + h * 64 + lc;
        bf16x2 k2 = *(const bf16x2*)&Kb[base];
        bf16x2 v2 = *(const bf16x2*)&V[base];
        kb[lr][lc] = (float)k2[0]; kb[lr][lc + 1] = (float)k2[1];
        vb[lr][lc] = (float)v2[0]; vb[lr][lc + 1] = (float)v2[1];
        __syncthreads();
#pragma unroll
        for (int tt = 0; tt < 8; ++tt) {
            float4 vv = *(const float4*)&vb[tt][dvq * 4];
            float4 kk = *(const float4*)&kb[tt][dkq * 4];
            float va[4] = {vv.x, vv.y, vv.z, vv.w};
            float ka[4] = {kk.x, kk.y, kk.z, kk.w};
#pragma unroll
            for (int i = 0; i < 4; ++i)
#pragma unroll
                for (int j = 0; j < 4; ++j)
                    acc[i][j] += va[i] * ka[j];
        }
        if (tid < 64) {
#pragma unroll
            for (int tt = 0; tt < 8; ++tt) ksacc += kb[tt][tid];
        }
        __syncthreads();
    }

    float* kvp = kv_part + ((size_t)tc * 64 + bh) * 4096;
#pragma unroll
    for (int i = 0; i < 4; ++i) {
        float4 wv = make_float4(acc[i][0], acc[i][1], acc[i][2], acc[i][3]);
        *(float4*)&kvp[(dvq * 4 + i) * 64 + dkq * 4] = wv;
    }
    if (tid < 64)
        ksum_part[((size_t)tc * 64 + bh) * 64 + tid] = ksacc;
}

// ------------------------------------------------------------- kv reduction
__global__ __launch_bounds__(256) void kv_reduce_kernel(
    const float* __restrict__ kv_part, const float* __restrict__ ksum_part,
    bf16* __restrict__ kvb, float* __restrict__ ksum)
{
    const int bh = blockIdx.x;
    const int tid = threadIdx.x;
    for (int e = tid; e < 4096; e += 256) {
        float s = 0.0f;
#pragma unroll
        for (int tc = 0; tc < 8; ++tc)
            s += kv_part[((size_t)tc * 64 + bh) * 4096 + e];
        kvb[(size_t)bh * 4096 + e] = (bf16)s;
    }
    if (tid < 64) {
        float s = 0.0f;
#pragma unroll
        for (int tc = 0; tc < 8; ++tc)
            s += ksum_part[((size_t)tc * 64 + bh) * 64 + tid];
        ksum[bh * 64 + tid] = s;
    }
}

// ------------------------------------------------------------------ attn
__global__ __launch_bounds__(256) void attn_kernel(
    const bf16* __restrict__ Q, const bf16* __restrict__ kvb,
    const float* __restrict__ ksum, bf16* __restrict__ attn)
{
    const int bh = blockIdx.y;
    const int b  = bh >> 4;
    const int h  = bh & 15;
    const int t0 = blockIdx.x * 128;

    __shared__ bf16 As[128 * 64];
    __shared__ bf16 Bs[64 * 64];
    __shared__ float ksum_s[64];
    __shared__ float norm_s[128];

    const int tid  = threadIdx.x;
    const int wave = tid >> 6;
    const int lane = tid & 63;

    const bf16* Qbase = Q + ((size_t)(b * T_) + t0) * 1024 + h * 64;

#pragma unroll
    for (int r2 = 0; r2 < 4; ++r2) {
        const int c   = r2 * 256 + wave * 64 + lane;
        const int row = c >> 3;
        const int ko  = (c & 7) * 8;
        char* l = (char*)As + (size_t)(r2 * 256 + wave * 64) * 16;
        async_ld16(Qbase + (size_t)row * 1024 + ko, l);
    }
    {
        const float4* src = (const float4*)(kvb + (size_t)bh * 4096);
        float4* dst = (float4*)Bs;
        for (int e = tid; e < 512; e += 256) dst[e] = src[e];
    }
    if (tid < 64) ksum_s[tid] = ksum[bh * 64 + tid];
    __syncthreads();

    if (tid < 128) {
        const bf16x8* qp = (const bf16x8*)(Qbase + (size_t)tid * 1024);
        float s = 0.0f;
#pragma unroll
        for (int u = 0; u < 8; ++u) {
            bf16x8 v = qp[u];
#pragma unroll
            for (int e = 0; e < 8; ++e) s += (float)v[e] * ksum_s[u * 8 + e];
        }
        norm_s[tid] = 1.0f / (s + EPS_);
    }
    __syncthreads();

    const int fr  = lane & 15;
    const int fkq = lane >> 4;
    f32x4 acc[2][4] = {};
#pragma unroll
    for (int ks = 0; ks < 2; ++ks) {
        bf16x8 af[2], bfr[4];
#pragma unroll
        for (int i = 0; i < 2; ++i)
            af[i] = *(const bf16x8*)&As[(wave * 32 + i * 16 + fr) * 64 + ks * 32 + fkq * 8];
#pragma unroll
        for (int j = 0; j < 4; ++j)
            bfr[j] = *(const bf16x8*)&Bs[(j * 16 + fr) * 64 + ks * 32 + fkq * 8];
#pragma unroll
        for (int i = 0; i < 2; ++i)
#pragma unroll
            for (int j = 0; j < 4; ++j)
                acc[i][j] = __builtin_amdgcn_mfma_f32_16x16x32_bf16(
                    af[i], bfr[j], acc[i][j], 0, 0, 0);
    }

    bf16* out = attn + ((size_t)(b * T_) + t0) * 1024 + h * 64;
#pragma unroll
    for (int i = 0; i < 2; ++i)
#pragma unroll
        for (int j = 0; j < 4; ++j)
#pragma unroll
            for (int r = 0; r < 4; ++r) {
                const int row = wave * 32 + i * 16 + fkq * 4 + r;
                const int col = j * 16 + fr;
                out[(size_t)row * 1024 + col] = (bf16)(acc[i][j][r] * norm_s[row]);
            }
}

// ---------------------------------------------------------------- launcher
extern "C" void kernel_launch(void* const* d_in, const int* in_sizes, int n_in,
                              void* d_out, int out_size, void* d_ws, size_t ws_size,
                              hipStream_t stream) {
    const float* query = (const float*)d_in[0];
    const float* key_  = (const float*)d_in[1];
    const float* value = (const float*)d_in[2];
    const float* Wq = (const float*)d_in[3];
    const float* bq = (const float*)d_in[4];
    const float* Wk = (const float*)d_in[5];
    const float* bk = (const float*)d_in[6];
    const float* Wv = (const float*)d_in[7];
    const float* bv = (const float*)d_in[8];
    const float* Wo = (const float*)d_in[9];
    const float* bo = (const float*)d_in[10];

    char* ws = (char*)d_ws;
    char* out8 = (char*)d_out;
    const size_t MB = 1024 * 1024;
    bf16* WqT = (bf16*)(ws + 0 * MB);
    bf16* WkT = (bf16*)(ws + 2 * MB);
    bf16* WvT = (bf16*)(ws + 4 * MB);
    bf16* WoT = (bf16*)(ws + 6 * MB);
    bf16* CVT = (bf16*)(ws + 8 * MB);                    // 32 MiB, reused 3x
    float* kv_part   = (float*)(ws + 40 * MB);           // 8 MiB
    float* ksum_part = (float*)(ws + 48 * MB);           // 128 KiB
    bf16*  kvb  = (bf16*)(ws + 48 * MB + 128 * 1024);    // 512 KiB
    float* ksum = (float*)(ws + 48 * MB + 640 * 1024);   // 16 KiB

    bf16* KB   = (bf16*)out8;                            // d_out [0,32)
    bf16* VB   = (bf16*)(out8 + 32 * MB);                // d_out [32,64)
    bf16* Qb   = (bf16*)out8;                            // reused after kv
    bf16* ATTN = CVT;                                    // reuses CVT slot

    TPtrs tp;
    tp.s[0] = Wq;  tp.s[1] = Wk;  tp.s[2] = Wv;  tp.s[3] = Wo;
    tp.d[0] = WqT; tp.d[1] = WkT; tp.d[2] = WvT; tp.d[3] = WoT;
    transpose4<<<dim3(32, 32, 4), dim3(32, 8, 1), 0, stream>>>(tp);

    const int CVT_BLOCKS = M_ * 1024 / 8 / 256;          // 8192
    const dim3 G256(4, 64);                              // N/256 x M/256

    cvt_kernel<<<CVT_BLOCKS, 256, 0, stream>>>(key_, CVT);
    gemm256_kernel<1, 0><<<G256, 512, 0, stream>>>(CVT, WkT, bk, KB, M_, 1024, 1024);

    cvt_kernel<<<CVT_BLOCKS, 256, 0, stream>>>(value, CVT);
    gemm256_kernel<0, 0><<<G256, 512, 0, stream>>>(CVT, WvT, bv, VB, M_, 1024, 1024);

    kv_partial_kernel<<<dim3(8, 64), 256, 0, stream>>>(KB, VB, kv_part, ksum_part);
    kv_reduce_kernel<<<dim3(64), 256, 0, stream>>>(kv_part, ksum_part, kvb, ksum);

    cvt_kernel<<<CVT_BLOCKS, 256, 0, stream>>>(query, CVT);
    gemm256_kernel<1, 0><<<G256, 512, 0, stream>>>(CVT, WqT, bq, Qb, M_, 1024, 1024);

    attn_kernel<<<dim3(32, 64), 256, 0, stream>>>(Qb, kvb, ksum, ATTN);

    gemm256_kernel<0, 1><<<G256, 512, 0, stream>>>(ATTN, WoT, bo, (float*)d_out, M_, 1024, 1024);
}